// Round 1
// baseline (107.826 us; speedup 1.0000x reference)
//
#include <hip/hip_runtime.h>
#include <math.h>

#define NUM_CLASSES 16
#define MARGIN_F 0.3f
#define EPS_F 1e-8f
#define READY_MAGIC 0x13579BDF

// ws layout (as float*):
//   [0..255]  : D16 distance matrix (row-major, D16[c1*16+c2])
//   [256..258]: accumulators {rank_sum, per_sum, valid_cnt}
//   [259]     : cnt1 (int)  — grid barrier arrival counter
//   [260]     : cnt2 (int)  — completion counter for finalize
//   [261]     : ready (int) — gate flag (ws is poisoned 0xAA; block 0 zeroes
//               counters then release-stores READY_MAGIC; every block
//               acquire-spins on it before touching any counter)
//
// Single fused kernel: grid = 256 blocks = 256 CUs, ~1.2 KB LDS, low VGPR
// -> all blocks co-resident -> in-kernel spin barrier is deadlock-free.

__global__ __launch_bounds__(256) void k_fused(const float* __restrict__ x, int Dm,
                                               const int* __restrict__ targets, int B,
                                               const int* __restrict__ ua, int T,
                                               float* __restrict__ D16,
                                               float* __restrict__ acc,
                                               int* __restrict__ cnt1,
                                               int* __restrict__ cnt2,
                                               int* __restrict__ ready,
                                               float* __restrict__ out) {
    __shared__ int   fi[NUM_CLASSES];
    __shared__ float red[4][3];
    __shared__ float sD[256];
    __shared__ float sP[NUM_CLASSES];

    const int t   = threadIdx.x;
    const int bid = blockIdx.x;

    // Block 0 zeroes cross-block state, then opens the gate.
    if (bid == 0 && t == 0) {
        __hip_atomic_store(&acc[0], 0.0f, __ATOMIC_RELAXED, __HIP_MEMORY_SCOPE_AGENT);
        __hip_atomic_store(&acc[1], 0.0f, __ATOMIC_RELAXED, __HIP_MEMORY_SCOPE_AGENT);
        __hip_atomic_store(&acc[2], 0.0f, __ATOMIC_RELAXED, __HIP_MEMORY_SCOPE_AGENT);
        __hip_atomic_store(cnt1, 0, __ATOMIC_RELAXED, __HIP_MEMORY_SCOPE_AGENT);
        __hip_atomic_store(cnt2, 0, __ATOMIC_RELAXED, __HIP_MEMORY_SCOPE_AGENT);
        __hip_atomic_store(ready, READY_MAGIC, __ATOMIC_RELEASE, __HIP_MEMORY_SCOPE_AGENT);
    }

    if (t < NUM_CLASSES) fi[t] = 0x7fffffff;
    __syncthreads();

    // Ballot-based first-occurrence scan (redundant per block, ~0.6 us, parallel).
    const int lane     = t & 63;
    const int waveBase = t & ~63;
    int myMin = 0x7fffffff;            // lane c (<16) tracks class c
    for (int base = waveBase; base < B; base += 256) {
        int v = (base + lane < B) ? targets[base + lane] : -1;
        #pragma unroll
        for (int c = 0; c < NUM_CLASSES; ++c) {
            unsigned long long m = __ballot(v == c);
            if (lane == c && m != 0ULL) {
                int cand = base + (__ffsll((long long)m) - 1);
                myMin = min(myMin, cand);
            }
        }
    }
    if (lane < NUM_CLASSES && myMin != 0x7fffffff) atomicMin(&fi[lane], myMin);
    __syncthreads();

    // Phase 1: this block's (c1,c2) pair distance. Dm=1024 -> one float4/lane.
    const int pair = bid;
    int i1 = fi[pair >> 4], i2 = fi[pair & 15];
    if (i1 == 0x7fffffff) i1 = 0;      // argmax over all-False returns 0
    if (i2 == 0x7fffffff) i2 = 0;
    const float4* __restrict__ x1 = (const float4*)(x + (long)i1 * Dm);
    const float4* __restrict__ x2 = (const float4*)(x + (long)i2 * Dm);
    const int n4 = Dm >> 2;
    float dot = 0.f, s1 = 0.f, s2 = 0.f;
    for (int k = t; k < n4; k += 256) {
        float4 a = x1[k], b = x2[k];
        dot = fmaf(a.x, b.x, fmaf(a.y, b.y, fmaf(a.z, b.z, fmaf(a.w, b.w, dot))));
        s1  = fmaf(a.x, a.x, fmaf(a.y, a.y, fmaf(a.z, a.z, fmaf(a.w, a.w, s1))));
        s2  = fmaf(b.x, b.x, fmaf(b.y, b.y, fmaf(b.z, b.z, fmaf(b.w, b.w, s2))));
    }
    #pragma unroll
    for (int off = 32; off > 0; off >>= 1) {
        dot += __shfl_down(dot, off);
        s1  += __shfl_down(s1, off);
        s2  += __shfl_down(s2, off);
    }
    const int wave = t >> 6;
    if (lane == 0) { red[wave][0] = dot; red[wave][1] = s1; red[wave][2] = s2; }
    __syncthreads();

    // Publish distance + grid barrier (t==0 spins; other waves park at barrier).
    if (t == 0) {
        float Dd = 0.f, A = 0.f, Bq = 0.f;
        #pragma unroll
        for (int w = 0; w < 4; ++w) { Dd += red[w][0]; A += red[w][1]; Bq += red[w][2]; }
        float d2 = A + Bq - 2.0f * Dd;   // c1==c2 -> exactly 0 (identical FMA sequences)
        float d  = sqrtf(fmaxf(d2, 1e-12f));
        __hip_atomic_store(&D16[pair], d, __ATOMIC_RELAXED, __HIP_MEMORY_SCOPE_AGENT);
        while (__hip_atomic_load(ready, __ATOMIC_ACQUIRE, __HIP_MEMORY_SCOPE_AGENT) != READY_MAGIC)
            __builtin_amdgcn_s_sleep(1);
        __hip_atomic_fetch_add(cnt1, 1, __ATOMIC_ACQ_REL, __HIP_MEMORY_SCOPE_AGENT);
        while (__hip_atomic_load(cnt1, __ATOMIC_ACQUIRE, __HIP_MEMORY_SCOPE_AGENT) < 256)
            __builtin_amdgcn_s_sleep(1);
    }
    __syncthreads();

    // Pull full D16 via agent-scope atomic loads (L2-coherent, bypasses L1).
    sD[t] = __hip_atomic_load(&D16[t], __ATOMIC_RELAXED, __HIP_MEMORY_SCOPE_AGENT);
    if (t < NUM_CLASSES) sP[t] = (fi[t] != 0x7fffffff) ? 1.0f : 0.0f;
    __syncthreads();

    // Phase 2: triplet reduction over T.
    float r = 0.f, pp = 0.f, cntv = 0.f;
    for (int i = bid * 256 + t; i < T; i += 256 * 256) {
        int a = ua[3 * i + 0];
        int b = ua[3 * i + 1];
        int c = ua[3 * i + 2];
        float valid = sP[a] * sP[b] * sP[c];
        float dap = sD[(a << 4) | b];
        float dan = sD[(a << 4) | c];
        float rank = fmaxf(dap - dan + MARGIN_F, 0.0f);
        float sap = 1.0f / (dap + 1.0f);
        float san = 1.0f / (dan + 1.0f);
        float per = -logf(sap / (sap + san) + EPS_F);
        r    += valid * rank;
        pp   += valid * per;
        cntv += valid;
    }
    #pragma unroll
    for (int off = 32; off > 0; off >>= 1) {
        r    += __shfl_down(r, off);
        pp   += __shfl_down(pp, off);
        cntv += __shfl_down(cntv, off);
    }
    if (lane == 0) { red[wave][0] = r; red[wave][1] = pp; red[wave][2] = cntv; }
    __syncthreads();

    if (t == 0) {
        float R = 0.f, P = 0.f, C = 0.f;
        #pragma unroll
        for (int w = 0; w < 4; ++w) { R += red[w][0]; P += red[w][1]; C += red[w][2]; }
        atomicAdd(&acc[0], R);
        atomicAdd(&acc[1], P);
        atomicAdd(&acc[2], C);
        __threadfence();
        int done = atomicAdd(cnt2, 1);
        if (done == 255) {             // last block finalizes
            float Rs = __hip_atomic_load(&acc[0], __ATOMIC_RELAXED, __HIP_MEMORY_SCOPE_AGENT);
            float Ps = __hip_atomic_load(&acc[1], __ATOMIC_RELAXED, __HIP_MEMORY_SCOPE_AGENT);
            float Cs = __hip_atomic_load(&acc[2], __ATOMIC_RELAXED, __HIP_MEMORY_SCOPE_AGENT);
            float nv = fmaxf(Cs, 1.0f);
            float lh = Rs / nv;
            float lp = Ps / nv;
            out[0] = lh + lp;
            out[1] = lh;
            out[2] = lp;
        }
    }
}

extern "C" void kernel_launch(void* const* d_in, const int* in_sizes, int n_in,
                              void* d_out, int out_size, void* d_ws, size_t ws_size,
                              hipStream_t stream) {
    // setup_inputs order:
    // 0: preds_mat (unused)  1: preds_sub (unused)  2: inputs (B,D) f32
    // 3: targets_mat (B,) int  4: targets_sub (unused)  5: user_answers (T,3) int
    const float* x       = (const float*)d_in[2];
    const int*   targets = (const int*)d_in[3];
    const int*   ua      = (const int*)d_in[5];
    float* out = (float*)d_out;

    int B  = in_sizes[3];
    int Dm = in_sizes[2] / B;
    int T  = in_sizes[5] / 3;

    float* ws    = (float*)d_ws;
    float* D16   = ws;               // 256 floats
    float* acc   = ws + 256;         // 3 floats
    int*   cnt1  = (int*)(ws + 259);
    int*   cnt2  = (int*)(ws + 260);
    int*   ready = (int*)(ws + 261);

    k_fused<<<256, 256, 0, stream>>>(x, Dm, targets, B, ua, T,
                                     D16, acc, cnt1, cnt2, ready, out);
}

// Round 2
// 91.169 us; speedup vs baseline: 1.1827x; 1.1827x over previous
//
#include <hip/hip_runtime.h>
#include <math.h>

#define NUM_CLASSES 16
#define MARGIN_F 0.3f
#define EPS_F 1e-8f

// ws layout (as float*):
//   [0..255]   : D16 distance matrix (row-major, D16[c1*16+c2])
//   [256..271] : present flags (1.0f / 0.0f)
//   [272..274] : accumulators {rank_sum, per_sum, valid_cnt}
//   [275]      : block completion counter (int)
//
// Two-kernel structure (fused+grid-barrier variant measured +8us WORSE:
// 256 spinner waves on one L2 line across 8 XCDs costs more than the
// HW kernel boundary. Keep the boundary.)

// k_dist: 136 blocks (c1<=c2 pairs) x 256 threads. Each block REDUNDANTLY
// ballot-scans targets for first-occurrence indices (16 KB, L2-broadcast),
// then computes its pair distance and writes BOTH symmetric entries.
// d2 = s1+s2-2*dot is bit-symmetric under operand swap (IEEE mul/add
// commute, FMA chains identical), so this is bit-identical to the old
// one-block-per-ordered-pair version.
__global__ __launch_bounds__(256) void k_dist(const float* __restrict__ x, int Dm,
                                              const int* __restrict__ targets, int B,
                                              float* __restrict__ D16,
                                              float* __restrict__ wsPres,
                                              float* __restrict__ wsAcc,
                                              int* __restrict__ wsCnt) {
    __shared__ int   fi[NUM_CLASSES];
    __shared__ float red[4][3];
    int t = threadIdx.x;
    if (t < NUM_CLASSES) fi[t] = 0x7fffffff;
    __syncthreads();

    // Ballot-based first-occurrence scan (16 cmp/ballot per 64-chunk).
    int lane = t & 63;
    int waveBase = t & ~63;
    int myMin = 0x7fffffff;            // lane c (<16) tracks class c
    for (int base = waveBase; base < B; base += 256) {
        int v = (base + lane < B) ? targets[base + lane] : -1;
        #pragma unroll
        for (int c = 0; c < NUM_CLASSES; ++c) {
            unsigned long long m = __ballot(v == c);
            if (lane == c && m != 0ULL) {
                int cand = base + (__ffsll((long long)m) - 1);
                myMin = min(myMin, cand);
            }
        }
    }
    if (lane < NUM_CLASSES && myMin != 0x7fffffff) atomicMin(&fi[lane], myMin);
    __syncthreads();

    // Block 0 publishes present flags and zeroes accumulators (ws poisoned 0xAA).
    if (blockIdx.x == 0) {
        if (t < NUM_CLASSES) wsPres[t] = (fi[t] != 0x7fffffff) ? 1.0f : 0.0f;
        if (t >= 32 && t < 35) wsAcc[t - 32] = 0.0f;
        if (t == 35) *wsCnt = 0;
    }

    // Decode upper-triangle pair index: bid -> (c1,c2), c1<=c2.
    int p = blockIdx.x, c1 = 0;
    while (p >= NUM_CLASSES - c1) { p -= NUM_CLASSES - c1; ++c1; }
    int c2 = c1 + p;

    int i1 = fi[c1], i2 = fi[c2];
    if (i1 == 0x7fffffff) i1 = 0;      // argmax over all-False returns 0
    if (i2 == 0x7fffffff) i2 = 0;
    const float4* __restrict__ x1 = (const float4*)(x + (long)i1 * Dm);
    const float4* __restrict__ x2 = (const float4*)(x + (long)i2 * Dm);
    int n4 = Dm >> 2;
    float dot = 0.f, s1 = 0.f, s2 = 0.f;
    for (int k = t; k < n4; k += 256) {
        float4 a = x1[k], b = x2[k];
        dot = fmaf(a.x, b.x, fmaf(a.y, b.y, fmaf(a.z, b.z, fmaf(a.w, b.w, dot))));
        s1  = fmaf(a.x, a.x, fmaf(a.y, a.y, fmaf(a.z, a.z, fmaf(a.w, a.w, s1))));
        s2  = fmaf(b.x, b.x, fmaf(b.y, b.y, fmaf(b.z, b.z, fmaf(b.w, b.w, s2))));
    }
    #pragma unroll
    for (int off = 32; off > 0; off >>= 1) {
        dot += __shfl_down(dot, off);
        s1  += __shfl_down(s1, off);
        s2  += __shfl_down(s2, off);
    }
    int wave = t >> 6;
    if (lane == 0) { red[wave][0] = dot; red[wave][1] = s1; red[wave][2] = s2; }
    __syncthreads();
    if (t == 0) {
        float D = 0.f, A = 0.f, Bq = 0.f;
        #pragma unroll
        for (int w = 0; w < 4; ++w) { D += red[w][0]; A += red[w][1]; Bq += red[w][2]; }
        float d2 = A + Bq - 2.0f * D;  // c1==c2 -> exactly 0 (identical FMA sequences)
        float d  = sqrtf(fmaxf(d2, 1e-12f));
        D16[(c1 << 4) | c2] = d;
        D16[(c2 << 4) | c1] = d;       // s2+s1 rounds identically to s1+s2
    }
}

// kB: triple reduction + last-block finalize. 4 triplets/thread via three
// 16B-aligned int4 loads (48 B per group, 48 % 16 == 0 for all three).
__global__ __launch_bounds__(256) void kB(const int* __restrict__ ua, int T,
                                          const float* __restrict__ D16,
                                          const float* __restrict__ wsPres,
                                          float* __restrict__ wsAcc,
                                          int* __restrict__ wsCnt,
                                          float* __restrict__ out) {
    __shared__ float sD[256];
    __shared__ float sP[NUM_CLASSES];
    __shared__ float sRed[4][3];
    __shared__ bool  amLast;
    int t = threadIdx.x;
    sD[t] = D16[t];
    if (t < NUM_CLASSES) sP[t] = wsPres[t];
    __syncthreads();

    float r = 0.f, pp = 0.f, cnt = 0.f;

    auto acc1 = [&](int a, int b, int c) {
        float valid = sP[a] * sP[b] * sP[c];
        float dap = sD[(a << 4) | b];
        float dan = sD[(a << 4) | c];
        float rank = fmaxf(dap - dan + MARGIN_F, 0.0f);
        float sap = 1.0f / (dap + 1.0f);
        float san = 1.0f / (dan + 1.0f);
        float per = -logf(sap / (sap + san) + EPS_F);
        r   += valid * rank;
        pp  += valid * per;
        cnt += valid;
    };

    int nG = T >> 2;                     // groups of 4 triplets
    int gid = blockIdx.x * blockDim.x + t;
    int stride = gridDim.x * blockDim.x;
    const int4* __restrict__ ua4 = (const int4*)ua;
    for (int g = gid; g < nG; g += stride) {
        int4 v0 = ua4[3 * g + 0];
        int4 v1 = ua4[3 * g + 1];
        int4 v2 = ua4[3 * g + 2];
        acc1(v0.x, v0.y, v0.z);
        acc1(v0.w, v1.x, v1.y);
        acc1(v1.z, v1.w, v2.x);
        acc1(v2.y, v2.z, v2.w);
    }
    for (int i = (nG << 2) + gid; i < T; i += stride) {   // tail (T % 4)
        acc1(ua[3 * i + 0], ua[3 * i + 1], ua[3 * i + 2]);
    }

    #pragma unroll
    for (int off = 32; off > 0; off >>= 1) {
        r   += __shfl_down(r, off);
        pp  += __shfl_down(pp, off);
        cnt += __shfl_down(cnt, off);
    }
    int wave = t >> 6, lane = t & 63;
    if (lane == 0) { sRed[wave][0] = r; sRed[wave][1] = pp; sRed[wave][2] = cnt; }
    __syncthreads();
    if (t == 0) {
        float R = 0.f, P = 0.f, C = 0.f;
        #pragma unroll
        for (int w = 0; w < 4; ++w) { R += sRed[w][0]; P += sRed[w][1]; C += sRed[w][2]; }
        atomicAdd(&wsAcc[0], R);
        atomicAdd(&wsAcc[1], P);
        atomicAdd(&wsAcc[2], C);
        __threadfence();
        int done = atomicAdd(wsCnt, 1);
        amLast = (done == (int)gridDim.x - 1);
    }
    __syncthreads();
    if (amLast && t == 0) {
        float R  = atomicAdd(&wsAcc[0], 0.0f);   // coherent device-scope reads
        float P  = atomicAdd(&wsAcc[1], 0.0f);
        float C  = atomicAdd(&wsAcc[2], 0.0f);
        float nv = fmaxf(C, 1.0f);
        float lh = R / nv;
        float lp = P / nv;
        out[0] = lh + lp;
        out[1] = lh;
        out[2] = lp;
    }
}

extern "C" void kernel_launch(void* const* d_in, const int* in_sizes, int n_in,
                              void* d_out, int out_size, void* d_ws, size_t ws_size,
                              hipStream_t stream) {
    // setup_inputs order:
    // 0: preds_mat (unused)  1: preds_sub (unused)  2: inputs (B,D) f32
    // 3: targets_mat (B,) int  4: targets_sub (unused)  5: user_answers (T,3) int
    const float* x       = (const float*)d_in[2];
    const int*   targets = (const int*)d_in[3];
    const int*   ua      = (const int*)d_in[5];
    float* out = (float*)d_out;

    int B  = in_sizes[3];
    int Dm = in_sizes[2] / B;
    int T  = in_sizes[5] / 3;

    float* ws     = (float*)d_ws;
    float* D16    = ws;              // 256 floats
    float* wsPres = ws + 256;        // 16 floats
    float* wsAcc  = ws + 272;        // 3 floats
    int*   wsCnt  = (int*)(ws + 275);

    int nPairs = NUM_CLASSES * (NUM_CLASSES + 1) / 2;   // 136
    k_dist<<<nPairs, 256, 0, stream>>>(x, Dm, targets, B, D16, wsPres, wsAcc, wsCnt);
    kB<<<128, 256, 0, stream>>>(ua, T, D16, wsPres, wsAcc, wsCnt, out);
}